// Round 4
// baseline (3279.034 us; speedup 1.0000x reference)
//
#include <hip/hip_runtime.h>
#include <stdint.h>

#define SEQ  256
#define BATCH 256
#define HID  1024
#define NCLS 10

// 128 WGs: 4 row-groups (64 rows) x 32 col-groups (32 cols), 256 thr / 4 waves.
// W_hh lives in REGISTERS (hi+lo), kt-split across waves; h exchanged through
// global in MFMA-fragment-linear layout (fully coalesced 16B/lane accesses);
// flag-array barrier (no atomic RMW contention).
#define G_R 4
#define G_C 32
#define NWG (G_R * G_C)         // 128
#define THREADS 256
#define NWAVE 4
#define KT 32                   // k-tiles of K=32 over HID
#define KT_W (KT / NWAVE)       // 8 per wave
#define CT 2                    // two 16-col tiles per WG (COLS_WG=32)

typedef __attribute__((ext_vector_type(8))) short bf16x8;
typedef __attribute__((ext_vector_type(4))) float f32x4;

__device__ __forceinline__ unsigned short f2bf(float f) {
  unsigned u = __builtin_bit_cast(unsigned, f);
  u = (u + 0x7FFFu + ((u >> 16) & 1u)) >> 16;
  return (unsigned short)u;
}
__device__ __forceinline__ float bf2f(unsigned short h) {
  unsigned u = ((unsigned)h) << 16;
  return __builtin_bit_cast(float, u);
}
__device__ __forceinline__ float fast_tanh(float x) {
  float ax = __builtin_fabsf(x);
  float e = __expf(2.0f * ax);
  float t = 1.0f - 2.0f / (e + 1.0f);
  return __builtin_copysignf(t, x);
}

__global__ __launch_bounds__(THREADS, 1) void rnn_persistent(
    const float* __restrict__ x, const float* __restrict__ Whx,
    const float* __restrict__ Whh, const float* __restrict__ Wph,
    const float* __restrict__ bh, const float* __restrict__ bp,
    float* __restrict__ out, unsigned char* __restrict__ ws)
{
  // cross-wave partial sums (kt-split reduction): 24 KiB
  __shared__ f32x4 red[NWAVE][NWAVE - 1][CT][4][16];
  // per-step output staging in fragment order: 4 KiB
  __shared__ unsigned short hstage[NWAVE][64][8];

  const int g    = blockIdx.x;
  const int tid  = threadIdx.x;
  const int lane = tid & 63;
  const int wv   = tid >> 6;       // wave 0..3: K-quarter owner + row-tile owner
  const int l15  = lane & 15;
  const int q    = lane >> 4;

  const int gr = g >> 5;           // row-group 0..3 (rows gr*64..+63)
  const int gc = g & 31;           // col-group == the kt-block index of our cols
  const int r0 = gr * 64;
  const int n0 = gc * 32;

  unsigned* flg = (unsigned*)ws + (size_t)gr * 512;          // 32 slots x 64B
  unsigned short* hbase = (unsigned short*)(ws + 8192);
  const size_t PLANE = (size_t)BATCH * HID;                  // 262144 elems
  // plane layout: elem(row,k) at ((R*32+kt)*64 + qk*16 + (row&15))*8 + j,
  // R=row>>4, kt=k>>5, kk=k&31, qk=(kk>>2)&3, j=(kk&3)|((kk>>4)<<2)
  // == MFMA 16x16x32 A-fragment-linear (operand mapping validated r1-r3).

  // ---- prologue: this wave's W_hh fragments (hi+lo) into REGISTERS
  bf16x8 Bhi[KT_W][CT], Blo[KT_W][CT];
#pragma unroll
  for (int kk2 = 0; kk2 < KT_W; ++kk2) {
#pragma unroll
    for (int ct = 0; ct < CT; ++ct) {
#pragma unroll
      for (int j = 0; j < 8; ++j) {
        int k = (wv * KT_W + kk2) * 32 + 4 * q + (j & 3) + 16 * (j >> 2);
        int c = n0 + ct * 16 + l15;
        float w = Whh[(size_t)k * HID + c];
        unsigned short hi = f2bf(w);
        unsigned short lo = f2bf(w - bf2f(hi));
        Bhi[kk2][ct][j] = (short)hi;
        Blo[kk2][ct][j] = (short)lo;
      }
    }
  }

  // per-lane epilogue constants
  float whx_v[CT], bh_v[CT];
#pragma unroll
  for (int ct = 0; ct < CT; ++ct) {
    int n = n0 + ct * 16 + l15;
    whx_v[ct] = Whx[n];
    bh_v[ct]  = bh[n];
  }
  const int crow0 = r0 + wv * 16 + q * 4;   // this lane's 4 epilogue rows

  // ---- sequential time steps
  for (int t = 0; t < SEQ; ++t) {
    const int wb = t & 1;
    f32x4 acc[NWAVE][CT];
#pragma unroll
    for (int rt = 0; rt < NWAVE; ++rt)
#pragma unroll
      for (int ct = 0; ct < CT; ++ct) acc[rt][ct] = (f32x4){0.f, 0.f, 0.f, 0.f};

    if (t > 0) {
      const volatile bf16x8* Ap =
          (const volatile bf16x8*)(hbase + (size_t)(wb ^ 1) * PLANE);
      bf16x8 A[KT_W][NWAVE];
      // issue all 32 coalesced 16B fragment loads up front
#pragma unroll
      for (int kk2 = 0; kk2 < KT_W; ++kk2)
#pragma unroll
        for (int rt = 0; rt < NWAVE; ++rt)
          A[kk2][rt] = Ap[(size_t)(((gr * 4 + rt) * 32) + (wv * KT_W + kk2)) * 64 + lane];
      // 128 MFMAs consume them as they land
#pragma unroll
      for (int kk2 = 0; kk2 < KT_W; ++kk2)
#pragma unroll
        for (int ct = 0; ct < CT; ++ct)
#pragma unroll
          for (int rt = 0; rt < NWAVE; ++rt) {
            acc[rt][ct] = __builtin_amdgcn_mfma_f32_16x16x32_bf16(A[kk2][rt], Bhi[kk2][ct], acc[rt][ct], 0, 0, 0);
            acc[rt][ct] = __builtin_amdgcn_mfma_f32_16x16x32_bf16(A[kk2][rt], Blo[kk2][ct], acc[rt][ct], 0, 0, 0);
          }
    }

    // ---- kt-split partials for non-owned row-tiles -> LDS
    f32x4 own[CT];
#pragma unroll
    for (int rt = 0; rt < NWAVE; ++rt) {
      if (rt == wv) {
#pragma unroll
        for (int ct = 0; ct < CT; ++ct) own[ct] = acc[rt][ct];
      } else {
        int slot = rt < wv ? rt : rt - 1;
#pragma unroll
        for (int ct = 0; ct < CT; ++ct) red[wv][slot][ct][q][l15] = acc[rt][ct];
      }
    }
    __syncthreads();

    // ---- reduce own tile + epilogue into fragment-order LDS staging
    float xr[4];
#pragma unroll
    for (int r = 0; r < 4; ++r) xr[r] = x[(size_t)(crow0 + r) * SEQ + t];

#pragma unroll
    for (int ct = 0; ct < CT; ++ct) {
      f32x4 s = own[ct];
#pragma unroll
      for (int w2 = 0; w2 < NWAVE; ++w2) {
        if (w2 != wv) {
          int slot = wv < w2 ? wv : wv - 1;
          s += red[w2][slot][ct][q][l15];
        }
      }
#pragma unroll
      for (int r = 0; r < 4; ++r) {
        float val = s[r] + xr[r] * whx_v[ct] + bh_v[ct];
        // fragment coords for (row16=q*4+r, kk=ct*16+l15):
        hstage[wv][(l15 >> 2) * 16 + q * 4 + r][(l15 & 3) | (ct << 2)] =
            f2bf(fast_tanh(val));
      }
    }
    __syncthreads();

    // ---- one coalesced 16B store per lane: wave wv stores fragment R=gr*4+wv, kt=gc
    {
      bf16x8 frag = *(const bf16x8*)&hstage[wv][lane][0];
      volatile bf16x8* Hd = (volatile bf16x8*)(hbase + (size_t)wb * PLANE);
      Hd[(size_t)(((gr * 4 + wv) * 32) + gc) * 64 + lane] = frag;
    }
    __syncthreads();   // drains each wave's vmcnt -> h at coherence point

    // ---- flag-array row-group barrier (no atomic RMW)
    if (wv == 0) {
      if (lane == 0)
        __hip_atomic_store(flg + gc * 16, (unsigned)(t + 1),
                           __ATOMIC_RELAXED, __HIP_MEMORY_SCOPE_AGENT);
      const unsigned tgt = (unsigned)(t + 1);
      for (;;) {
        unsigned f = tgt;
        if (lane < 32)
          f = __hip_atomic_load(flg + lane * 16, __ATOMIC_RELAXED,
                                __HIP_MEMORY_SCOPE_AGENT);
        if (__all((int)(f >= tgt))) break;
        __builtin_amdgcn_s_sleep(1);
      }
    }
    __syncthreads();
  }

  // ---- final projection: out = h_last @ Wph + bp (h_last in plane 1)
  if (wv < 2) {
    const unsigned short* F = hbase + PLANE;
    int b = g * 2 + wv;               // rows gr*64 + gc*2 + wv: own row-group
    const int Rb = b >> 4, lb = b & 15;
    float p[NCLS];
#pragma unroll
    for (int c = 0; c < NCLS; ++c) p[c] = 0.f;
    for (int k = lane; k < HID; k += 64) {
      int kt = k >> 5, kk = k & 31;
      int qk = (kk >> 2) & 3;
      int j  = (kk & 3) | ((kk >> 4) << 2);
      size_t off = ((size_t)(Rb * 32 + kt) * 64 + qk * 16 + lb) * 8 + j;
      unsigned short hraw = __hip_atomic_load(F + off, __ATOMIC_RELAXED,
                                              __HIP_MEMORY_SCOPE_AGENT);
      float hv = bf2f(hraw);
      const float* wp = Wph + (size_t)k * NCLS;
#pragma unroll
      for (int c = 0; c < NCLS; ++c) p[c] += hv * wp[c];
    }
#pragma unroll
    for (int c = 0; c < NCLS; ++c) {
      float v = p[c];
      for (int off = 32; off > 0; off >>= 1) v += __shfl_down(v, off, 64);
      if (lane == 0) out[b * NCLS + c] = v + bp[c];
    }
  }
}

extern "C" void kernel_launch(void* const* d_in, const int* in_sizes, int n_in,
                              void* d_out, int out_size, void* d_ws, size_t ws_size,
                              hipStream_t stream) {
  const float* x   = (const float*)d_in[0];
  const float* Whx = (const float*)d_in[1];
  const float* Whh = (const float*)d_in[2];
  const float* Wph = (const float*)d_in[3];
  const float* bh  = (const float*)d_in[4];
  const float* bp  = (const float*)d_in[5];

  hipMemsetAsync(d_ws, 0, 8192, stream);   // barrier flags

  hipLaunchKernelGGL(rnn_persistent, dim3(NWG), dim3(THREADS), 0, stream,
                     x, Whx, Whh, Wph, bh, bp,
                     (float*)d_out, (unsigned char*)d_ws);
}

// Round 6
// 1890.001 us; speedup vs baseline: 1.7349x; 1.7349x over previous
//
#include <hip/hip_runtime.h>
#include <stdint.h>

#define SEQ   256
#define BATCH 256
#define HID   1024
#define NCLS  10

// 128 WGs = 8 batch-groups (32 batch rows) x 16 hid-blocks (64 hid rows).
// Transposed recurrence: C = W^T (A-operand, registers) x h^T (B-operand).
// 8 waves per WG kt-split K=1024 (4 kstacks of 32 each); cross-wave LDS reduce.
// Sync group = 16 WGs of a batch-group. Agent-scope exchange (r3-proven):
// volatile loads (L1/L2-bypass) + atomic write-through stores + flag array.
#define NWG     128
#define THREADS 512
#define PLANEB  (32 * 16 * 64 * 16)   // 32 kstacks x 16 bfrags x 64 lanes x 16B

typedef __attribute__((ext_vector_type(8))) short bf16x8;
typedef __attribute__((ext_vector_type(4))) float f32x4;

__device__ __forceinline__ unsigned short f2bf(float f) {
  unsigned u = __builtin_bit_cast(unsigned, f);
  u = (u + 0x7FFFu + ((u >> 16) & 1u)) >> 16;
  return (unsigned short)u;
}
__device__ __forceinline__ float bf2f(unsigned short h) {
  unsigned u = ((unsigned)h) << 16;
  return __builtin_bit_cast(float, u);
}
__device__ __forceinline__ float fast_tanh(float x) {
  float ax = __builtin_fabsf(x);
  float e = __expf(2.0f * ax);
  float t = 1.0f - 2.0f / (e + 1.0f);
  return __builtin_copysignf(t, x);
}

__global__ __launch_bounds__(THREADS, 2) void rnn_lockstep(
    const float* __restrict__ x, const float* __restrict__ Whx,
    const float* __restrict__ Whh, const float* __restrict__ Wph,
    const float* __restrict__ bh, const float* __restrict__ bp,
    float* __restrict__ out, unsigned char* __restrict__ ws)
{
  // cross-wave kt-split reduction: [tile 0..7][producer slot 0..6][lane] f32x4
  __shared__ f32x4 red[8][7][64];     // 57344 B

  const int tid  = threadIdx.x;
  const int lane = tid & 63;
  const int wv   = tid >> 6;          // 0..7
  const int l15  = lane & 15;
  const int q    = lane >> 4;

  const int gb = blockIdx.x >> 4;     // batch group 0..7 (rows gb*32..+31)
  const int s  = blockIdx.x & 15;     // hid block 0..15 (hid s*64..+63)

  unsigned* flags = (unsigned*)ws;               // 128 slots x 64B = 8 KiB
  unsigned char* p0 = ws + 8192;                 // h^T plane 0 (512 KiB)
  unsigned char* p1 = p0 + PLANEB;               // h^T plane 1

  // ---- prologue: this wave's W^T A-fragments (hi+lo) into registers.
  // A-frag (validated r1-r4 mapping): lane(q,l15) holds A[row=l15][k=4q+(j&3)+16*(j>>2)]
  // A = W^T tile: row = hid_out = s*64+rt*16+l15, k = ks*32 + ... ; value = Whh[k][hid_out]
  bf16x8 whi[4][4], wlo[4][4];
#pragma unroll
  for (int i = 0; i < 4; ++i) {
    const int ks = wv * 4 + i;
#pragma unroll
    for (int rt = 0; rt < 4; ++rt) {
      const int n = s * 64 + rt * 16 + l15;
#pragma unroll
      for (int j = 0; j < 8; ++j) {
        int k = ks * 32 + 4 * q + (j & 3) + 16 * (j >> 2);
        float w = Whh[(size_t)k * HID + n];
        unsigned short hi = f2bf(w);
        whi[i][rt][j] = (short)hi;
        wlo[i][rt][j] = (short)f2bf(w - bf2f(hi));
      }
    }
  }

  // owner constants: wave wv owns C tile (rt_o = wv>>1, bt_o = wv&1)
  const int rt_o = wv >> 1, bt_o = wv & 1;
  const int b_own = gb * 32 + bt_o * 16 + l15;       // this lane's batch row
  const float* xrow = x + (size_t)b_own * SEQ;
  const float4 whx4 = *(const float4*)(Whx + s * 64 + rt_o * 16 + q * 4);
  const float4 bh4  = *(const float4*)(bh  + s * 64 + rt_o * 16 + q * 4);
  // output fragment: kstack = s*2+(wv>>2), bfrag = gb*2+bt_o, 8B half = rt_o&1
  const size_t woff = ((size_t)((s * 2 + (wv >> 2)) * 16 + gb * 2 + bt_o) * 64 + lane) * 16
                    + (size_t)(rt_o & 1) * 8;

  // ---- sequential time steps
  for (int t = 0; t < SEQ; ++t) {
    unsigned char* wp = (t & 1) ? p1 : p0;
    const unsigned char* rp = (t & 1) ? p0 : p1;

    f32x4 acc[4][2];
#pragma unroll
    for (int rt = 0; rt < 4; ++rt)
#pragma unroll
      for (int bt = 0; bt < 2; ++bt) acc[rt][bt] = (f32x4){0.f, 0.f, 0.f, 0.f};

    if (t > 0) {
      // wait for the 16 producers of this batch-group (wave 7 polls, others park at barrier)
      if (wv == 7) {
        const unsigned tgt = (unsigned)t;
        for (;;) {
          unsigned f = tgt;
          if (lane < 16)
            f = __hip_atomic_load(flags + (gb * 16 + lane) * 16,
                                  __ATOMIC_RELAXED, __HIP_MEMORY_SCOPE_AGENT);
          if (__all((int)(f >= tgt))) break;
          __builtin_amdgcn_s_sleep(1);
        }
      }
      __syncthreads();

      // 8 coalesced 16B volatile loads (L1/L2-bypass, r3-proven), batched -> one latency
      bf16x8 hf[4][2];
#pragma unroll
      for (int i = 0; i < 4; ++i)
#pragma unroll
        for (int bt = 0; bt < 2; ++bt)
          hf[i][bt] = *(const volatile bf16x8*)
              (rp + ((size_t)((wv * 4 + i) * 16 + gb * 2 + bt) * 64 + lane) * 16);
      __builtin_amdgcn_sched_barrier(0);

      // 64 MFMAs over this wave's 4 kstacks
#pragma unroll
      for (int i = 0; i < 4; ++i)
#pragma unroll
        for (int bt = 0; bt < 2; ++bt)
#pragma unroll
          for (int rt = 0; rt < 4; ++rt) {
            acc[rt][bt] = __builtin_amdgcn_mfma_f32_16x16x32_bf16(whi[i][rt], hf[i][bt], acc[rt][bt], 0, 0, 0);
            acc[rt][bt] = __builtin_amdgcn_mfma_f32_16x16x32_bf16(wlo[i][rt], hf[i][bt], acc[rt][bt], 0, 0, 0);
          }
    }

    // ---- cross-wave reduction: write the 7 non-owned tiles (all indices static)
#pragma unroll
    for (int T = 0; T < 8; ++T)
      if (T != wv)
        red[T][(wv > T) ? (wv - 1) : wv][lane] = acc[T >> 1][T & 1];
    __syncthreads();

    f32x4 ssum = acc[rt_o][bt_o];
#pragma unroll
    for (int pr = 0; pr < 7; ++pr) ssum += red[wv][pr][lane];

    // ---- epilogue: C/D row = hid q*4+r, col = batch l15 (transposed layout).
    // Next-step B-frag element j' = r + 4*(rt_o&1) at this very lane -> pack 4x bf16, one 8B store.
    const float xb = xrow[t];
    const float v0 = fast_tanh(ssum[0] + xb * whx4.x + bh4.x);
    const float v1 = fast_tanh(ssum[1] + xb * whx4.y + bh4.y);
    const float v2 = fast_tanh(ssum[2] + xb * whx4.z + bh4.z);
    const float v3 = fast_tanh(ssum[3] + xb * whx4.w + bh4.w);
    unsigned long long pk =
        (unsigned long long)f2bf(v0) | ((unsigned long long)f2bf(v1) << 16) |
        ((unsigned long long)f2bf(v2) << 32) | ((unsigned long long)f2bf(v3) << 48);
    __hip_atomic_store((unsigned long long*)(wp + woff), pk,
                       __ATOMIC_RELAXED, __HIP_MEMORY_SCOPE_AGENT);

    __syncthreads();   // every wave drains vmcnt before s_barrier -> stores at L3
    if (tid == 0)
      __hip_atomic_store(flags + (gb * 16 + s) * 16, (unsigned)(t + 1),
                         __ATOMIC_RELAXED, __HIP_MEMORY_SCOPE_AGENT);
  }

  // ---- final projection (one WG per batch-group): out = h_last @ Wph + bp
  if (s != 0) return;
  if (wv == 7) {
    for (;;) {
      unsigned f = 256u;
      if (lane < 16)
        f = __hip_atomic_load(flags + (gb * 16 + lane) * 16,
                              __ATOMIC_RELAXED, __HIP_MEMORY_SCOPE_AGENT);
      if (__all((int)(f >= 256u))) break;
      __builtin_amdgcn_s_sleep(1);
    }
  }
  __syncthreads();

  float pr0[NCLS], pr1[NCLS];
#pragma unroll
  for (int c = 0; c < NCLS; ++c) { pr0[c] = 0.f; pr1[c] = 0.f; }
#pragma unroll
  for (int i = 0; i < 4; ++i) {
    const int ks = wv * 4 + i;
#pragma unroll
    for (int bt = 0; bt < 2; ++bt) {
      bf16x8 fr = *(const volatile bf16x8*)
          (p1 + ((size_t)(ks * 16 + gb * 2 + bt) * 64 + lane) * 16);
#pragma unroll
      for (int j = 0; j < 8; ++j) {
        int k = ks * 32 + 4 * q + (j & 3) + 16 * (j >> 2);
        float hv = bf2f((unsigned short)fr[j]);
        const float* wrow = Wph + (size_t)k * NCLS;
#pragma unroll
        for (int c = 0; c < NCLS; ++c) {
          if (bt == 0) pr0[c] += hv * wrow[c];
          else         pr1[c] += hv * wrow[c];
        }
      }
    }
  }
#pragma unroll
  for (int c = 0; c < NCLS; ++c) {
    pr0[c] += __shfl_xor(pr0[c], 16, 64); pr0[c] += __shfl_xor(pr0[c], 32, 64);
    pr1[c] += __shfl_xor(pr1[c], 16, 64); pr1[c] += __shfl_xor(pr1[c], 32, 64);
  }
  float* projl = (float*)&red[0][0][0];   // reuse LDS: [8 wv][2 bt][16 b][10 c]
  if (q == 0) {
#pragma unroll
    for (int c = 0; c < NCLS; ++c) {
      projl[((wv * 2 + 0) * 16 + l15) * NCLS + c] = pr0[c];
      projl[((wv * 2 + 1) * 16 + l15) * NCLS + c] = pr1[c];
    }
  }
  __syncthreads();
  if (tid < 32 * NCLS) {
    int bl = tid / NCLS, c = tid - bl * NCLS;
    float sum = bp[c];
#pragma unroll
    for (int w = 0; w < 8; ++w)
      sum += projl[((w * 2 + (bl >> 4)) * 16 + (bl & 15)) * NCLS + c];
    out[(size_t)(gb * 32 + bl) * NCLS + c] = sum;
  }
}

extern "C" void kernel_launch(void* const* d_in, const int* in_sizes, int n_in,
                              void* d_out, int out_size, void* d_ws, size_t ws_size,
                              hipStream_t stream) {
  const float* x   = (const float*)d_in[0];
  const float* Whx = (const float*)d_in[1];
  const float* Whh = (const float*)d_in[2];
  const float* Wph = (const float*)d_in[3];
  const float* bh  = (const float*)d_in[4];
  const float* bp  = (const float*)d_in[5];

  hipMemsetAsync(d_ws, 0, 8192, stream);   // flag array

  hipLaunchKernelGGL(rnn_lockstep, dim3(NWG), dim3(THREADS), 0, stream,
                     x, Whx, Whh, Wph, bh, bp,
                     (float*)d_out, (unsigned char*)d_ws);
}